// Round 9
// baseline (1621.729 us; speedup 1.0000x reference)
//
#include <hip/hip_runtime.h>
#include <math.h>

#define LOG0f (-1.0e30f)
#define ACTIVE_TH (-1.0e29f)
#define PRUNE_TH (-9.0f)
#define VCAB 128
#define HSZ 4096
#define HMASK (HSZ - 1)
#define MAXN 2052
#define HEMPTY 0xFFFFFFFFu

// JAX-exact logaddexp: max + log1p(exp(-|a-b|)) in f32
__device__ __forceinline__ float lae(float a, float b) {
    float mx = fmaxf(a, b);
    float d = fabsf(a - b);
    return mx + log1pf(expf(-d));
}
// monotonic float->uint transform (order-preserving)
__device__ __forceinline__ unsigned mono(float f) {
    unsigned u = __float_as_uint(f);
    return (u & 0x80000000u) ? ~u : (u | 0x80000000u);
}
__device__ __forceinline__ float mono_inv(unsigned m) {
    unsigned u = (m & 0x80000000u) ? (m & 0x7FFFFFFFu) : ~m;
    return __uint_as_float(u);
}
__device__ __forceinline__ unsigned rlaneu(unsigned x, int l) {
    return (unsigned)__builtin_amdgcn_readlane((int)x, l);
}
__device__ __forceinline__ float rlanef(float x, int l) {
    return __uint_as_float(rlaneu(__float_as_uint(x), l));
}
__device__ __forceinline__ unsigned rfl(unsigned x) {
    return (unsigned)__builtin_amdgcn_readfirstlane((int)x);
}
// select a[s] from a statically-indexed 8-array (cndmask chain)
__device__ __forceinline__ unsigned sel8u(const unsigned a[8], unsigned s) {
    unsigned r = a[0];
#pragma unroll
    for (int j = 1; j < 8; ++j) r = (s == (unsigned)j) ? a[j] : r;
    return r;
}

// wave-wide max of u32: DPP up-sweep into lane 63 (rocPRIM gfx9 ladder), readlane -> uniform
__device__ __forceinline__ unsigned wred_max_u32(unsigned x) {
    unsigned y;
    y = (unsigned)__builtin_amdgcn_update_dpp(0, (int)x, 0x111, 0xf, 0xf, false);  // row_shr:1
    x = (y > x) ? y : x;
    y = (unsigned)__builtin_amdgcn_update_dpp(0, (int)x, 0x112, 0xf, 0xf, false);  // row_shr:2
    x = (y > x) ? y : x;
    y = (unsigned)__builtin_amdgcn_update_dpp(0, (int)x, 0x114, 0xf, 0xf, false);  // row_shr:4
    x = (y > x) ? y : x;
    y = (unsigned)__builtin_amdgcn_update_dpp(0, (int)x, 0x118, 0xf, 0xf, false);  // row_shr:8
    x = (y > x) ? y : x;
    y = (unsigned)__builtin_amdgcn_update_dpp(0, (int)x, 0x142, 0xa, 0xf, false);  // row_bcast:15
    x = (y > x) ? y : x;
    y = (unsigned)__builtin_amdgcn_update_dpp(0, (int)x, 0x143, 0xc, 0xf, false);  // row_bcast:31
    x = (y > x) ? y : x;
    return (unsigned)__builtin_amdgcn_readlane((int)x, 63);
}

__global__ __launch_bounds__(64, 1)
void ctc_beam_kernel(const float* __restrict__ probs, const int* __restrict__ lengths,
                     const int* __restrict__ blank_p, int* __restrict__ out_seq,
                     int* __restrict__ out_len, int T) {
    __shared__ unsigned hsh[HSZ];        // dedup map (parent,label)->node: (hkey<<12)|id
    __shared__ unsigned nodeinfo[MAXN];  // (parent<<7)|label per node id
    __shared__ int sh_seq[256];

    const int lane = threadIdx.x;
    const int b = blockIdx.x;
    const int blank = (int)rfl((unsigned)blank_p[0]);
    const int length = (int)rfl((unsigned)lengths[b]);
    const float* __restrict__ P = probs + (size_t)b * T * VCAB;
    const int own = lane & 7;  // beam owned by this lane (lanes 0..7 authoritative)
    const unsigned kl16 = (lane < 8) ? ~(unsigned)lane : 0u;

    for (int i = lane; i < HSZ; i += 64) hsh[i] = HEMPTY;
    __syncthreads();

    // wave-uniform beam metadata (values always produced by readfirstlane/readlane)
    unsigned node8[8], par8[8], len8[8], last8[8];
#pragma unroll
    for (int j = 0; j < 8; ++j) {
        node8[j] = 0; par8[j] = 0xFFFu; len8[j] = 0; last8[j] = (unsigned)blank;
    }
    // per-lane own-beam probabilities (lane j authoritative for beam j)
    float pb_own = (own == 0) ? 0.0f : LOG0f;  // root: blank prob = log(1)
    float pnb_own = LOG0f;

    // per-lane prob layout: label `lane` in prL, label `lane+64` in prH
    float prL = P[lane];
    float prH = P[64 + lane];

#pragma clang loop unroll(disable)
    for (int t = 0; t < length; ++t) {
        // prefetch t+1 (clamped; last-iteration values unused)
        const int tn = (t + 1 < length) ? (t + 1) : (length - 1);
        float nprL = P[(size_t)tn * VCAB + lane];
        float nprH = P[(size_t)tn * VCAB + 64 + lane];

        float pt_own = lae(pb_own, pnb_own);
        unsigned long long bal = __ballot(pt_own > ACTIVE_TH);
        const unsigned actmask = (unsigned)bal & 0xFFu;
        const bool act_own = (actmask >> own) & 1u;
        const int len_own = (int)len8[own];
        const int last_own = (int)last8[own];

        // uniform per-beam prob tables (readlane from lanes 0..7)
        float pb8[8], pt8[8];
#pragma unroll
        for (int j = 0; j < 8; ++j) {
            pb8[j] = rlanef(pb_own, j);
            pt8[j] = rlanef(pt_own, j);
        }
        float prB = (blank < 64) ? rlanef(prL, blank) : rlanef(prH, blank - 64);
        float prv8[8];  // row prob at each beam's last label (uniform index)
#pragma unroll
        for (int j = 0; j < 8; ++j) {
            int lj = (int)last8[j];
            float a = rlanef(prL, lj & 63), c2 = rlanef(prH, lj & 63);
            prv8[j] = (lj < 64) ? a : c2;
        }

        // own parent match by node-id identity (ids content-faithful via dedup)
        int p_own = 0;
        bool matched = false;
        {
            bool gate = act_own && (len_own > 0);
            unsigned pown = par8[own];
#pragma unroll
            for (int j = 0; j < 8; ++j) {
                bool m = gate && ((actmask >> j) & 1u) && (node8[j] == pown);
                if (m) { p_own = j; matched = true; }
            }
        }
        float pbp = pb8[0], ptp = pt8[0];
        int lastp = (int)last8[0];
#pragma unroll
        for (int j = 1; j < 8; ++j) {
            bool m = (p_own == j);
            pbp = m ? pb8[j] : pbp;
            ptp = m ? pt8[j] : ptp;
            lastp = m ? (int)last8[j] : lastp;
        }
        float pprev = matched ? ((last_own == lastp) ? pbp : ptp) : LOG0f;
        float prLast = prv8[0];
#pragma unroll
        for (int j = 1; j < 8; ++j) prLast = (own == j) ? prv8[j] : prLast;

        float contb_own = pt_own + prB;
        float contnb_own = (len_own > 0) ? (lae(pnb_own, pprev) + prLast) : LOG0f;
        float tot_own = lae(contb_own, contnb_own);

        // uniform parent-index tables -> per-lane claimed-child masks
        const unsigned matched_mask = (unsigned)__ballot(matched) & 0xFFu;
        unsigned pidx8[8];
#pragma unroll
        for (int j = 0; j < 8; ++j) pidx8[j] = rlaneu((unsigned)p_own, j);
        unsigned cmaskL = 0, cmaskH = 0;  // bit i: label {lane,lane+64} is existing child of beam i
#pragma unroll
        for (int a = 0; a < 8; ++a) {
            if ((matched_mask >> a) & 1u) {  // uniform condition
                unsigned bit = 1u << pidx8[a];
                cmaskL |= (last8[a] == (unsigned)lane) ? bit : 0u;
                cmaskH |= (last8[a] == (unsigned)(lane + 64)) ? bit : 0u;
            }
        }

        // 16 ext candidates per lane: beam i = k>>1, label v = lane + (k&1)*64
        // ref index space: [0..7]=continuations, [8..8+1024)=extensions i*V+v
        unsigned kh0, kh1, kh2, kh3, kh4, kh5, kh6, kh7, kh8, kh9, kh10, kh11,
                 kh12, kh13, kh14, kh15, kh16;
#define MK(k, i, hi)                                                                     \
        do {                                                                             \
            float pv = (hi) ? prH : prL;                                                 \
            unsigned vv = (unsigned)lane + ((hi) ? 64u : 0u);                            \
            float prev = (vv == last8[i]) ? pb8[i] : pt8[i];                             \
            float val = pv + prev;                                                       \
            bool actb = (actmask >> (i)) & 1u;                                           \
            unsigned cm = (hi) ? cmaskH : cmaskL;                                        \
            bool bad = ((int)vv == blank) | (pv <= PRUNE_TH) | (!actb) |                 \
                       (bool)((cm >> (i)) & 1u);                                         \
            if (bad) val = LOG0f;                                                        \
            kh##k = mono(val);                                                           \
        } while (0);
        MK(0, 0, 0) MK(1, 0, 1) MK(2, 1, 0) MK(3, 1, 1)
        MK(4, 2, 0) MK(5, 2, 1) MK(6, 3, 0) MK(7, 3, 1)
        MK(8, 4, 0) MK(9, 4, 1) MK(10, 5, 0) MK(11, 5, 1)
        MK(12, 6, 0) MK(13, 6, 1) MK(14, 7, 0) MK(15, 7, 1)
#undef MK
        kh16 = (lane < 8) ? mono(tot_own) : 0u;

#define EXTKL(i, hi) (~(8u + (unsigned)((i) * 128 + (hi) * 64 + lane)))

        // local sorted top-3 cache (u64 keys, globally unique)
        unsigned long long m1 = 0ull, m2 = 0ull, m3 = 0ull;
#define INS(k, KL)                                                                       \
        do {                                                                             \
            unsigned long long key = (((unsigned long long)kh##k) << 32) | (unsigned)(KL); \
            bool g1 = key > m1, g2 = key > m2, g3 = key > m3;                            \
            unsigned long long t1 = g1 ? key : m1;                                       \
            unsigned long long t2 = g1 ? m1 : (g2 ? key : m2);                           \
            m3 = (g1 | g2) ? m2 : (g3 ? key : m3);                                       \
            m1 = t1; m2 = t2;                                                            \
        } while (0);
        INS(0, EXTKL(0, 0)) INS(1, EXTKL(0, 1)) INS(2, EXTKL(1, 0)) INS(3, EXTKL(1, 1))
        INS(4, EXTKL(2, 0)) INS(5, EXTKL(2, 1)) INS(6, EXTKL(3, 0)) INS(7, EXTKL(3, 1))
        INS(8, EXTKL(4, 0)) INS(9, EXTKL(4, 1)) INS(10, EXTKL(5, 0)) INS(11, EXTKL(5, 1))
        INS(12, EXTKL(6, 0)) INS(13, EXTKL(6, 1)) INS(14, EXTKL(7, 0)) INS(15, EXTKL(7, 1))
        INS(16, kl16)
#undef INS

        // top-8 extraction (named-scalar rounds): strictly-decreasing bound W
        unsigned long long W = ~0ull;
        unsigned A_0, A_1, A_2, A_3, A_4, A_5, A_6, A_7;
        unsigned B_0, B_1, B_2, B_3, B_4, B_5, B_6, B_7;
        unsigned extmask = 0, insPar = 0, insRes = 0;
        int insLab = 0;
        float npb_own = LOG0f, npnb_own = LOG0f;
        bool dead = false;
#define RS(k, KL)                                                                        \
        do {                                                                             \
            unsigned long long key = (((unsigned long long)kh##k) << 32) | (unsigned)(KL); \
            bool g = (key < W) && (key > c);                                             \
            c = g ? key : c;                                                             \
        } while (0);
#define ROUND(r)                                                                         \
        do {                                                                             \
            unsigned long long c = (m1 < W) ? m1 : ((m2 < W) ? m2 : ((m3 < W) ? m3 : 0ull)); \
            bool need = (c == 0ull) && !dead;                                            \
            if (__any(need)) {                                                           \
                if (need) {                                                              \
                    c = 0ull;                                                            \
                    RS(0, EXTKL(0, 0)) RS(1, EXTKL(0, 1)) RS(2, EXTKL(1, 0))             \
                    RS(3, EXTKL(1, 1)) RS(4, EXTKL(2, 0)) RS(5, EXTKL(2, 1))             \
                    RS(6, EXTKL(3, 0)) RS(7, EXTKL(3, 1)) RS(8, EXTKL(4, 0))             \
                    RS(9, EXTKL(4, 1)) RS(10, EXTKL(5, 0)) RS(11, EXTKL(5, 1))           \
                    RS(12, EXTKL(6, 0)) RS(13, EXTKL(6, 1)) RS(14, EXTKL(7, 0))          \
                    RS(15, EXTKL(7, 1)) RS(16, kl16)                                     \
                    if (c == 0ull) dead = true;                                          \
                    else { m1 = c; m2 = ~0ull; m3 = ~0ull; }                             \
                }                                                                        \
            }                                                                            \
            unsigned ch = (unsigned)(c >> 32), cl = (unsigned)c;                         \
            unsigned M = wred_max_u32(ch);                                               \
            unsigned lo2 = (ch == M) ? cl : 0u;                                          \
            unsigned L = wred_max_u32(lo2);                                              \
            W = (((unsigned long long)M) << 32) | L;                                     \
            unsigned sel = ~L;                                                           \
            if (sel < 8u) { /* continuation of beam sel */                               \
                float cb = rlanef(contb_own, (int)sel);                                  \
                float cn = rlanef(contnb_own, (int)sel);                                 \
                if (own == (r)) { npb_own = cb; npnb_own = cn; }                         \
                A_##r = rfl((sel8u(node8, sel) << 12) | sel8u(par8, sel));               \
                B_##r = rfl((sel8u(len8, sel) << 7) | sel8u(last8, sel));                \
            } else { /* extension (src s, label lab); pnb == sort value bitwise */       \
                unsigned e = sel - 8u;                                                   \
                unsigned s = e >> 7, lab = e & 127u;                                     \
                float val = mono_inv(M);                                                 \
                if (own == (r)) { npb_own = LOG0f; npnb_own = val; }                     \
                unsigned nd = sel8u(node8, s), ln = sel8u(len8, s);                      \
                A_##r = rfl(nd); /* node patched after hash; par = nd */                 \
                B_##r = rfl(((ln + 1u) << 7) | lab);                                     \
                extmask |= 1u << (r);                                                    \
                if (lane == (r)) { insPar = nd; insLab = (int)lab; }                     \
            }                                                                            \
        } while (0);
        ROUND(0) ROUND(1) ROUND(2) ROUND(3) ROUND(4) ROUND(5) ROUND(6) ROUND(7)
#undef ROUND
#undef RS
#undef EXTKL

        // dedup-hash inserts: lane r handles new beam r (deterministic pre-ids)
        if ((extmask >> lane) & 1u) {
            unsigned preid = 1u + 8u * (unsigned)t + (unsigned)lane;
            unsigned hkey = (insPar << 7) | (unsigned)insLab;
            unsigned entry = (hkey << 12) | preid;
            unsigned h = ((hkey * 2654435761u) >> 20) & HMASK;
            for (;;) {
                unsigned prev = atomicCAS(&hsh[h], HEMPTY, entry);
                if (prev == HEMPTY) { nodeinfo[preid] = hkey; insRes = preid; break; }
                if ((prev >> 12) == hkey) { insRes = prev & 0xFFFu; break; }
                h = (h + 1) & HMASK;
            }
        }
        // patch ext node ids via readlane from the inserting lane + commit
#define COMMIT(r)                                                                        \
        do {                                                                             \
            unsigned nd = A_##r >> 12;                                                   \
            if ((extmask >> (r)) & 1u) nd = rlaneu(insRes, (r)); /* uniform cond */      \
            node8[r] = nd; par8[r] = A_##r & 0xFFFu;                                     \
            len8[r] = B_##r >> 7; last8[r] = B_##r & 127u;                               \
        } while (0);
        COMMIT(0) COMMIT(1) COMMIT(2) COMMIT(3) COMMIT(4) COMMIT(5) COMMIT(6) COMMIT(7)
#undef COMMIT
        pb_own = npb_own; pnb_own = npnb_own;

        prL = nprL; prH = nprH;
    }

    // final argmax of totals (ties -> lowest index), then parent-walk reconstruction
    unsigned fh, fl;
    {
        float tot = lae(pb_own, pnb_own);
        fh = (lane < 8) ? mono(tot) : 0u;
        fl = (lane < 8) ? ~(unsigned)lane : 0u;
    }
    {
        unsigned M = wred_max_u32(fh);
        unsigned lo2 = (fh == M) ? fl : 0u;
        fl = wred_max_u32(lo2);
    }
    const int best = (int)(~fl);
    int L = 0;
    unsigned c = 0;
#pragma unroll
    for (int j = 0; j < 8; ++j)
        if (best == j) { L = (int)len8[j]; c = node8[j]; }
    if (lane == 0) {
        for (int k = L - 1; k >= 0; --k) {
            unsigned info = nodeinfo[c];
            sh_seq[k] = (int)(info & 127u);
            c = info >> 7;
        }
    }
    __syncthreads();
    for (int j = lane; j < T; j += 64)
        out_seq[(size_t)b * T + j] = (j < L) ? sh_seq[j] : 0;
    if (lane == 0) out_len[b] = L;
}

extern "C" void kernel_launch(void* const* d_in, const int* in_sizes, int n_in,
                              void* d_out, int out_size, void* d_ws, size_t ws_size,
                              hipStream_t stream) {
    const float* probs = (const float*)d_in[0];
    const int* lengths = (const int*)d_in[1];
    // d_in[2] = beam_width (fixed 8, compiled in); d_in[3] = blank_index
    const int* blank_p = (const int*)d_in[3];
    const int B = in_sizes[1];
    const int T = in_sizes[0] / (B * VCAB);
    int* out = (int*)d_out;
    ctc_beam_kernel<<<B, 64, 0, stream>>>(probs, lengths, blank_p, out,
                                          out + (size_t)B * T, T);
}

// Round 10
// 1285.883 us; speedup vs baseline: 1.2612x; 1.2612x over previous
//
#include <hip/hip_runtime.h>
#include <math.h>

#define LOG0f (-1.0e30f)
#define ACTIVE_TH (-1.0e29f)
#define PRUNE_TH (-9.0f)
#define VCAB 128
#define HSZ 4096
#define HMASK (HSZ - 1)
#define MAXN 2052
#define HEMPTY 0xFFFFFFFFu

// JAX-exact logaddexp: max + log1p(exp(-|a-b|)) in f32
__device__ __forceinline__ float lae(float a, float b) {
    float mx = fmaxf(a, b);
    float d = fabsf(a - b);
    return mx + log1pf(expf(-d));
}
// monotonic float->uint transform (order-preserving)
__device__ __forceinline__ unsigned mono(float f) {
    unsigned u = __float_as_uint(f);
    return (u & 0x80000000u) ? ~u : (u | 0x80000000u);
}
__device__ __forceinline__ float mono_inv(unsigned m) {
    unsigned u = (m & 0x80000000u) ? (m & 0x7FFFFFFFu) : ~m;
    return __uint_as_float(u);
}
__device__ __forceinline__ unsigned rlaneu(unsigned x, int l) {
    return (unsigned)__builtin_amdgcn_readlane((int)x, l);
}
__device__ __forceinline__ float rlanef(float x, int l) {
    return __uint_as_float(rlaneu(__float_as_uint(x), l));
}
// select a[s] from a statically-indexed 8-array (cndmask/cselect chain)
__device__ __forceinline__ unsigned sel8u(const unsigned a[8], unsigned s) {
    unsigned r = a[0];
#pragma unroll
    for (int j = 1; j < 8; ++j) r = (s == (unsigned)j) ? a[j] : r;
    return r;
}
__device__ __forceinline__ float sel8f(const float a[8], unsigned s) {
    float r = a[0];
#pragma unroll
    for (int j = 1; j < 8; ++j) r = (s == (unsigned)j) ? a[j] : r;
    return r;
}

// wave-wide max of u32: DPP up-sweep into lane 63 (rocPRIM gfx9 ladder), readlane -> uniform
__device__ __forceinline__ unsigned wred_max_u32(unsigned x) {
    unsigned y;
    y = (unsigned)__builtin_amdgcn_update_dpp(0, (int)x, 0x111, 0xf, 0xf, false);  // row_shr:1
    x = (y > x) ? y : x;
    y = (unsigned)__builtin_amdgcn_update_dpp(0, (int)x, 0x112, 0xf, 0xf, false);  // row_shr:2
    x = (y > x) ? y : x;
    y = (unsigned)__builtin_amdgcn_update_dpp(0, (int)x, 0x114, 0xf, 0xf, false);  // row_shr:4
    x = (y > x) ? y : x;
    y = (unsigned)__builtin_amdgcn_update_dpp(0, (int)x, 0x118, 0xf, 0xf, false);  // row_shr:8
    x = (y > x) ? y : x;
    y = (unsigned)__builtin_amdgcn_update_dpp(0, (int)x, 0x142, 0xa, 0xf, false);  // row_bcast:15
    x = (y > x) ? y : x;
    y = (unsigned)__builtin_amdgcn_update_dpp(0, (int)x, 0x143, 0xc, 0xf, false);  // row_bcast:31
    x = (y > x) ? y : x;
    return (unsigned)__builtin_amdgcn_readlane((int)x, 63);
}

__global__ __launch_bounds__(64)
void ctc_beam_kernel(const float* __restrict__ probs, const int* __restrict__ lengths,
                     const int* __restrict__ blank_p, int* __restrict__ out_seq,
                     int* __restrict__ out_len, int T) {
    __shared__ unsigned hsh[HSZ];        // dedup map (parent,label)->node: (hkey<<12)|id
    __shared__ unsigned nodeinfo[MAXN];  // (parent<<7)|label per node id
    __shared__ int sh_seq[256];

    const int lane = threadIdx.x;
    const int b = blockIdx.x;
    const int blank = blank_p[0];
    const int length = lengths[b];
    const float* __restrict__ P = probs + (size_t)b * T * VCAB;
    const float4* __restrict__ P4 = (const float4*)P;
    const int own = lane & 7;     // beam owned by this lane
    const int slice = lane >> 3;  // vocab slice [slice*16, +16)
    const int vbase = slice * 16;

    for (int i = lane; i < HSZ; i += 64) hsh[i] = HEMPTY;
    __syncthreads();

    // wave-uniform beam metadata
    unsigned node8[8], par8[8], len8[8], last8[8];
#pragma unroll
    for (int j = 0; j < 8; ++j) {
        node8[j] = 0; par8[j] = 0xFFFu; len8[j] = 0; last8[j] = (unsigned)blank;
    }
    // per-lane own-beam state (lane j authoritative for beam j; others replicas)
    float pb_own = (own == 0) ? 0.0f : LOG0f;  // root: blank prob = log(1)
    float pnb_own = LOG0f;
    int len_own = 0, last_own = blank;
    unsigned node_own = 0, par_own = 0xFFFu;

    // prefetch row 0: slice (float4 x4) + per-lane layout (labels lane, lane+64)
    float4 s0, s1, s2, s3;
    float prL, prH;
    {
        int base4 = (vbase >> 2);
        s0 = P4[base4]; s1 = P4[base4 + 1]; s2 = P4[base4 + 2]; s3 = P4[base4 + 3];
        prL = P[lane]; prH = P[64 + lane];
    }

#pragma clang loop unroll(disable)
    for (int t = 0; t < length; ++t) {
        // prefetch t+1
        float4 n0, n1, n2, n3;
        float nprL = 0.f, nprH = 0.f;
        n0 = n1 = n2 = n3 = make_float4(0.f, 0.f, 0.f, 0.f);
        if (t + 1 < length) {
            int base4 = (t + 1) * 32 + (vbase >> 2);
            n0 = P4[base4]; n1 = P4[base4 + 1]; n2 = P4[base4 + 2]; n3 = P4[base4 + 3];
            nprL = P[(size_t)(t + 1) * VCAB + lane];
            nprH = P[(size_t)(t + 1) * VCAB + 64 + lane];
        }

        float pt_own = lae(pb_own, pnb_own);
        unsigned long long bal = __ballot(pt_own > ACTIVE_TH);
        unsigned actmask = (unsigned)bal & 0xFFu;
        bool act_own = (actmask >> own) & 1u;

        // uniform per-beam tables via readlane (beam j authoritative on lane j)
        float pb8[8], pt8[8];
#pragma unroll
        for (int j = 0; j < 8; ++j) {
            pb8[j] = rlanef(pb_own, j);
            pt8[j] = rlanef(pt_own, j);
        }
        float prB = (blank < 64) ? rlanef(prL, blank) : rlanef(prH, blank - 64);
        float prv8[8];  // row prob at each beam's last label (uniform index)
#pragma unroll
        for (int j = 0; j < 8; ++j) {
            int lj = (int)last8[j];
            float a = rlanef(prL, lj & 63), c2 = rlanef(prH, lj & 63);
            prv8[j] = (lj < 64) ? a : c2;
        }

        // own parent match by node-id identity (ids content-faithful via dedup)
        int p_own = 0;
        bool matched = false;
        {
            bool gate = act_own && (len_own > 0);
#pragma unroll
            for (int j = 0; j < 8; ++j) {
                bool m = gate && ((actmask >> j) & 1u) && (node8[j] == par_own);
                if (m) { p_own = j; matched = true; }
            }
        }
        float pbp = pb8[0], ptp = pt8[0];
        int lastp = (int)last8[0];
#pragma unroll
        for (int j = 1; j < 8; ++j) {
            bool m = (p_own == j);
            pbp = m ? pb8[j] : pbp;
            ptp = m ? pt8[j] : ptp;
            lastp = m ? (int)last8[j] : lastp;
        }
        float pprev = matched ? ((last_own == lastp) ? pbp : ptp) : LOG0f;
        float prLast = prv8[0];
#pragma unroll
        for (int j = 1; j < 8; ++j) prLast = (own == j) ? prv8[j] : prLast;

        float contb_own = pt_own + prB;
        float contnb_own = (len_own > 0) ? (lae(pnb_own, pprev) + prLast) : LOG0f;
        float tot_own = lae(contb_own, contnb_own);

        // labels in my slice claimed as existing children of my beam
        unsigned claimed16 = 0;
#pragma unroll
        for (int j = 0; j < 8; ++j) {
            bool mj = ((actmask >> j) & 1u) && act_own && (node_own == par8[j]);
            bool ins = ((last8[j] >> 4) == (unsigned)slice);
            claimed16 |= (mj && ins) ? (1u << (last8[j] & 15u)) : 0u;
        }

        // candidate keys: 16 extensions (my beam x my slice) + cont on lanes 0..7
        // ref index space: [0..7]=continuations, [8..8+1024)=extensions i*V+v
        unsigned long long K[17];
#define MAKEK(c, pv)                                                                     \
        {                                                                                \
            int v = vbase + (c);                                                         \
            float prev = (v == last_own) ? pb_own : pt_own;                              \
            float val = (pv) + prev;                                                     \
            bool bad = (v == blank) | ((pv) <= PRUNE_TH) | (!act_own) |                  \
                       (bool)((claimed16 >> (c)) & 1u);                                  \
            if (bad) val = LOG0f;                                                        \
            K[c] = (((unsigned long long)mono(val)) << 32) |                             \
                   (unsigned)~(8u + (unsigned)(own * VCAB + v));                         \
        }
        MAKEK(0, s0.x) MAKEK(1, s0.y) MAKEK(2, s0.z) MAKEK(3, s0.w)
        MAKEK(4, s1.x) MAKEK(5, s1.y) MAKEK(6, s1.z) MAKEK(7, s1.w)
        MAKEK(8, s2.x) MAKEK(9, s2.y) MAKEK(10, s2.z) MAKEK(11, s2.w)
        MAKEK(12, s3.x) MAKEK(13, s3.y) MAKEK(14, s3.z) MAKEK(15, s3.w)
#undef MAKEK
        K[16] = (lane < 8)
                    ? ((((unsigned long long)mono(tot_own)) << 32) | (unsigned)~(unsigned)lane)
                    : 0ull;

        // local sorted top-3 cache
        unsigned long long m1 = 0ull, m2 = 0ull, m3 = 0ull;
#pragma unroll
        for (int k = 0; k < 17; ++k) {
            unsigned long long key = K[k];
            bool g1 = key > m1, g2 = key > m2, g3 = key > m3;
            unsigned long long t1 = g1 ? key : m1;
            unsigned long long t2 = g1 ? m1 : (g2 ? key : m2);
            m3 = (g1 | g2) ? m2 : (g3 ? key : m3);
            m1 = t1; m2 = t2;
        }

        // top-8 extraction: rounds emit only (selh, sell); decode deferred
        unsigned long long W = ~0ull;
        unsigned selh[8], sell[8];
        bool dead = false;
#pragma unroll
        for (int r = 0; r < 8; ++r) {
            unsigned long long c = (m1 < W) ? m1 : ((m2 < W) ? m2 : ((m3 < W) ? m3 : 0ull));
            bool need = (c == 0ull) && !dead;  // cache consumed -> bounded rescan (rare)
            if (__any(need)) {
                if (need) {
                    c = 0ull;
#pragma unroll
                    for (int k = 0; k < 17; ++k) {
                        bool g = (K[k] < W) && (K[k] > c);
                        c = g ? K[k] : c;
                    }
                    if (c == 0ull) dead = true;
                    else { m1 = c; m2 = ~0ull; m3 = ~0ull; }  // poison: rescan next time
                }
            }
            unsigned ch = (unsigned)(c >> 32), cl = (unsigned)c;
            unsigned M = wred_max_u32(ch);            // winner value word (uniform)
            unsigned lo2 = (ch == M) ? cl : 0u;
            unsigned L = wred_max_u32(lo2);           // winner ~refidx (max = lowest idx)
            W = (((unsigned long long)M) << 32) | L;
            selh[r] = M; sell[r] = L;
        }

        // uniform continuation-value tables (for per-lane decode)
        float cb8[8], cn8[8];
#pragma unroll
        for (int j = 0; j < 8; ++j) {
            cb8[j] = rlanef(contb_own, j);
            cn8[j] = rlanef(contnb_own, j);
        }

        // per-lane decode: every lane decodes round `own` (lanes 8..63 = replicas)
        unsigned myM = sel8u(selh, (unsigned)own);
        unsigned myL = sel8u(sell, (unsigned)own);
        unsigned sel = ~myL;
        bool iscont = sel < 8u;
        unsigned e = sel - 8u;
        unsigned s = iscont ? sel : (e >> 7);
        unsigned lab = e & 127u;
        unsigned nd = sel8u(node8, s);
        unsigned pr = sel8u(par8, s);
        unsigned ln = sel8u(len8, s);
        unsigned la = sel8u(last8, s);
        float cbs = sel8f(cb8, s);
        float cns = sel8f(cn8, s);
        float npb_own = iscont ? cbs : LOG0f;
        float npnb_own = iscont ? cns : mono_inv(myM);  // ext pnb == sort value bitwise
        // A=(node<<12)|par (ext: node patched after hash, par = src node)
        unsigned A = iscont ? ((nd << 12) | pr) : nd;
        unsigned Bv = iscont ? ((ln << 7) | la) : (((ln + 1u) << 7) | lab);
        unsigned long long extbal = __ballot(!iscont);
        unsigned extmask = (unsigned)extbal & 0xFFu;  // bit r: round r was an extension

        // dedup-hash inserts: lane r handles new beam r (deterministic pre-ids)
        unsigned insRes = 0;
        if ((extmask >> lane) & 1u) {
            unsigned preid = 1u + 8u * (unsigned)t + (unsigned)lane;
            unsigned hkey = (nd << 7) | lab;
            unsigned entry = (hkey << 12) | preid;
            unsigned h = ((hkey * 2654435761u) >> 20) & HMASK;
            for (;;) {
                unsigned prev = atomicCAS(&hsh[h], HEMPTY, entry);
                if (prev == HEMPTY) { nodeinfo[preid] = hkey; insRes = preid; break; }
                if ((prev >> 12) == hkey) { insRes = prev & 0xFFFu; break; }
                h = (h + 1) & HMASK;
            }
        }
        // commit: gather per-round state from lane r; patch ext node ids
#pragma unroll
        for (int r = 0; r < 8; ++r) {
            unsigned Ar = rlaneu(A, r);
            unsigned Br = rlaneu(Bv, r);
            unsigned nd2 = Ar >> 12;
            if ((extmask >> r) & 1u) nd2 = rlaneu(insRes, r);  // uniform condition
            node8[r] = nd2; par8[r] = Ar & 0xFFFu;
            len8[r] = Br >> 7; last8[r] = Br & 127u;
        }
        node_own = sel8u(node8, (unsigned)own);
        par_own = sel8u(par8, (unsigned)own);
        len_own = (int)sel8u(len8, (unsigned)own);
        last_own = (int)sel8u(last8, (unsigned)own);
        pb_own = npb_own; pnb_own = npnb_own;

        s0 = n0; s1 = n1; s2 = n2; s3 = n3;
        prL = nprL; prH = nprH;
    }

    // final argmax of totals (ties -> lowest index), then parent-walk reconstruction
    unsigned fh, fl;
    {
        float tot = lae(pb_own, pnb_own);
        fh = (lane < 8) ? mono(tot) : 0u;
        fl = (lane < 8) ? ~(unsigned)lane : 0u;
    }
    {
        unsigned M = wred_max_u32(fh);
        unsigned lo2 = (fh == M) ? fl : 0u;
        fl = wred_max_u32(lo2);
    }
    const int best = (int)(~fl);
    int L = 0;
    unsigned c = 0;
#pragma unroll
    for (int j = 0; j < 8; ++j)
        if (best == j) { L = (int)len8[j]; c = node8[j]; }
    if (lane == 0) {
        for (int k = L - 1; k >= 0; --k) {
            unsigned info = nodeinfo[c];
            sh_seq[k] = (int)(info & 127u);
            c = info >> 7;
        }
    }
    __syncthreads();
    for (int j = lane; j < T; j += 64)
        out_seq[(size_t)b * T + j] = (j < L) ? sh_seq[j] : 0;
    if (lane == 0) out_len[b] = L;
}

extern "C" void kernel_launch(void* const* d_in, const int* in_sizes, int n_in,
                              void* d_out, int out_size, void* d_ws, size_t ws_size,
                              hipStream_t stream) {
    const float* probs = (const float*)d_in[0];
    const int* lengths = (const int*)d_in[1];
    // d_in[2] = beam_width (fixed 8, compiled in); d_in[3] = blank_index
    const int* blank_p = (const int*)d_in[3];
    const int B = in_sizes[1];
    const int T = in_sizes[0] / (B * VCAB);
    int* out = (int*)d_out;
    ctc_beam_kernel<<<B, 64, 0, stream>>>(probs, lengths, blank_p, out,
                                          out + (size_t)B * T, T);
}

// Round 11
// 1174.944 us; speedup vs baseline: 1.3803x; 1.0944x over previous
//
#include <hip/hip_runtime.h>
#include <math.h>

#define LOG0f (-1.0e30f)
#define ACTIVE_TH (-1.0e29f)
#define PRUNE_TH (-9.0f)
#define VCAB 128
#define HSZ 4096
#define HMASK (HSZ - 1)
#define MAXN 2052
#define HEMPTY 0xFFFFFFFFu

// JAX-exact logaddexp: max + log1p(exp(-|a-b|)) in f32
__device__ __forceinline__ float lae(float a, float b) {
    float mx = fmaxf(a, b);
    float d = fabsf(a - b);
    return mx + log1pf(expf(-d));
}
// monotonic float->uint transform (order-preserving)
__device__ __forceinline__ unsigned mono(float f) {
    unsigned u = __float_as_uint(f);
    return (u & 0x80000000u) ? ~u : (u | 0x80000000u);
}
__device__ __forceinline__ float mono_inv(unsigned m) {
    unsigned u = (m & 0x80000000u) ? (m & 0x7FFFFFFFu) : ~m;
    return __uint_as_float(u);
}
__device__ __forceinline__ unsigned rlaneu(unsigned x, int l) {
    return (unsigned)__builtin_amdgcn_readlane((int)x, l);
}
__device__ __forceinline__ float rlanef(float x, int l) {
    return __uint_as_float(rlaneu(__float_as_uint(x), l));
}
// select a[s] from a statically-indexed 8-array (cndmask chain)
__device__ __forceinline__ unsigned sel8u(const unsigned a[8], unsigned s) {
    unsigned r = a[0];
#pragma unroll
    for (int j = 1; j < 8; ++j) r = (s == (unsigned)j) ? a[j] : r;
    return r;
}

// wave-wide max of u32: DPP up-sweep into lane 63 (rocPRIM gfx9 ladder), readlane -> uniform
__device__ __forceinline__ unsigned wred_max_u32(unsigned x) {
    unsigned y;
    y = (unsigned)__builtin_amdgcn_update_dpp(0, (int)x, 0x111, 0xf, 0xf, false);  // row_shr:1
    x = (y > x) ? y : x;
    y = (unsigned)__builtin_amdgcn_update_dpp(0, (int)x, 0x112, 0xf, 0xf, false);  // row_shr:2
    x = (y > x) ? y : x;
    y = (unsigned)__builtin_amdgcn_update_dpp(0, (int)x, 0x114, 0xf, 0xf, false);  // row_shr:4
    x = (y > x) ? y : x;
    y = (unsigned)__builtin_amdgcn_update_dpp(0, (int)x, 0x118, 0xf, 0xf, false);  // row_shr:8
    x = (y > x) ? y : x;
    y = (unsigned)__builtin_amdgcn_update_dpp(0, (int)x, 0x142, 0xa, 0xf, false);  // row_bcast:15
    x = (y > x) ? y : x;
    y = (unsigned)__builtin_amdgcn_update_dpp(0, (int)x, 0x143, 0xc, 0xf, false);  // row_bcast:31
    x = (y > x) ? y : x;
    return (unsigned)__builtin_amdgcn_readlane((int)x, 63);
}

#define REP8(X) X(0) X(1) X(2) X(3) X(4) X(5) X(6) X(7)
#define REP7(X) X(1) X(2) X(3) X(4) X(5) X(6) X(7)
// select named scalars n_0..n_7 by runtime s
#define SEL8N(out, s, n)                                                        \
    do {                                                                        \
        out = n##_0;                                                            \
        out = ((s) == 1u) ? n##_1 : out; out = ((s) == 2u) ? n##_2 : out;       \
        out = ((s) == 3u) ? n##_3 : out; out = ((s) == 4u) ? n##_4 : out;       \
        out = ((s) == 5u) ? n##_5 : out; out = ((s) == 6u) ? n##_6 : out;       \
        out = ((s) == 7u) ? n##_7 : out;                                        \
    } while (0)

__global__ __launch_bounds__(64)
void ctc_beam_kernel(const float* __restrict__ probs, const int* __restrict__ lengths,
                     const int* __restrict__ blank_p, int* __restrict__ out_seq,
                     int* __restrict__ out_len, int T) {
    __shared__ unsigned hsh[HSZ];        // dedup map (parent,label)->node: (hkey<<12)|id
    __shared__ unsigned nodeinfo[MAXN];  // (parent<<7)|label per node id
    __shared__ int sh_seq[256];

    const int lane = threadIdx.x;
    const int b = blockIdx.x;
    const int blank = blank_p[0];
    const int length = lengths[b];
    const float* __restrict__ P = probs + (size_t)b * T * VCAB;
    const float4* __restrict__ P4 = (const float4*)P;
    const int own = lane & 7;     // beam owned by this lane
    const int slice = lane >> 3;  // vocab slice [slice*16, +16)
    const int vbase = slice * 16;

    for (int i = lane; i < HSZ; i += 64) hsh[i] = HEMPTY;
    __syncthreads();

    // wave-uniform beam metadata (static indexing only; v3/v5-proven clean)
    unsigned node8[8], par8[8], len8[8], last8[8];
#pragma unroll
    for (int j = 0; j < 8; ++j) {
        node8[j] = 0; par8[j] = 0xFFFu; len8[j] = 0; last8[j] = (unsigned)blank;
    }
    // per-lane own-beam state (lane j authoritative for beam j; others replicas)
    float pb_own = (own == 0) ? 0.0f : LOG0f;  // root: blank prob = log(1)
    float pnb_own = LOG0f;
    int len_own = 0, last_own = blank;
    unsigned node_own = 0, par_own = 0xFFFu;

    // prefetch row 0: slice (float4 x4) + per-lane layout (labels lane, lane+64)
    float4 s0, s1, s2, s3;
    float prL, prH;
    {
        int base4 = (vbase >> 2);
        s0 = P4[base4]; s1 = P4[base4 + 1]; s2 = P4[base4 + 2]; s3 = P4[base4 + 3];
        prL = P[lane]; prH = P[64 + lane];
    }

#pragma clang loop unroll(disable)
    for (int t = 0; t < length; ++t) {
        // branchless clamped prefetch of t+1 (values unused on final iteration)
        const int tn = (t + 1 < length) ? (t + 1) : (length - 1);
        float4 n0, n1, n2, n3;
        float nprL, nprH;
        {
            int base4 = tn * 32 + (vbase >> 2);
            n0 = P4[base4]; n1 = P4[base4 + 1]; n2 = P4[base4 + 2]; n3 = P4[base4 + 3];
            nprL = P[(size_t)tn * VCAB + lane];
            nprH = P[(size_t)tn * VCAB + 64 + lane];
        }

        float pt_own = lae(pb_own, pnb_own);
        unsigned long long bal = __ballot(pt_own > ACTIVE_TH);
        unsigned actmask = (unsigned)bal & 0xFFu;
        bool act_own = (actmask >> own) & 1u;

        // uniform per-beam tables (named scalars; readlane from lanes 0..7)
#define TBL(j) float pb8_##j = rlanef(pb_own, j); float pt8_##j = rlanef(pt_own, j);
        REP8(TBL)
#undef TBL
        float prB = (blank < 64) ? rlanef(prL, blank) : rlanef(prH, blank - 64);
#define PRV(j)                                                                  \
        float prv8_##j;                                                         \
        {                                                                       \
            int lj = (int)last8[j];                                             \
            float a_ = rlanef(prL, lj & 63), c_ = rlanef(prH, lj & 63);         \
            prv8_##j = (lj < 64) ? a_ : c_;                                     \
        }
        REP8(PRV)
#undef PRV

        // own parent match by node-id identity (ids content-faithful via dedup)
        int p_own = 0;
        bool matched = false;
        {
            bool gate = act_own && (len_own > 0);
#define PM(j)                                                                   \
            {                                                                   \
                bool m_ = gate && ((actmask >> j) & 1u) && (node8[j] == par_own); \
                if (m_) { p_own = j; matched = true; }                          \
            }
            REP8(PM)
#undef PM
        }
        float pbp = pb8_0, ptp = pt8_0;
        int lastp = (int)last8[0];
#define PSEL(j)                                                                 \
        {                                                                       \
            bool m_ = (p_own == j);                                             \
            pbp = m_ ? pb8_##j : pbp;                                           \
            ptp = m_ ? pt8_##j : ptp;                                           \
            lastp = m_ ? (int)last8[j] : lastp;                                 \
        }
        REP7(PSEL)
#undef PSEL
        float pprev = matched ? ((last_own == lastp) ? pbp : ptp) : LOG0f;
        float prLast = prv8_0;
#define PLSEL(j) prLast = (own == j) ? prv8_##j : prLast;
        REP7(PLSEL)
#undef PLSEL

        float contb_own = pt_own + prB;
        float contnb_own = (len_own > 0) ? (lae(pnb_own, pprev) + prLast) : LOG0f;
        float tot_own = lae(contb_own, contnb_own);

        // labels in my slice claimed as existing children of my beam
        unsigned claimed16 = 0;
#pragma unroll
        for (int j = 0; j < 8; ++j) {
            bool mj = ((actmask >> j) & 1u) && act_own && (node_own == par8[j]);
            bool ins = ((last8[j] >> 4) == (unsigned)slice);
            claimed16 |= (mj && ins) ? (1u << (last8[j] & 15u)) : 0u;
        }

        // candidate keys: 16 extensions (my beam x my slice) + cont on lanes 0..7
        // ref index space: [0..7]=continuations, [8..8+1024)=extensions i*V+v
        unsigned long long K[17];
#define MAKEK(c, pv)                                                                     \
        {                                                                                \
            int v = vbase + (c);                                                         \
            float prev = (v == last_own) ? pb_own : pt_own;                              \
            float val = (pv) + prev;                                                     \
            bool bad = (v == blank) | ((pv) <= PRUNE_TH) | (!act_own) |                  \
                       (bool)((claimed16 >> (c)) & 1u);                                  \
            if (bad) val = LOG0f;                                                        \
            K[c] = (((unsigned long long)mono(val)) << 32) |                             \
                   (unsigned)~(8u + (unsigned)(own * VCAB + v));                         \
        }
        MAKEK(0, s0.x) MAKEK(1, s0.y) MAKEK(2, s0.z) MAKEK(3, s0.w)
        MAKEK(4, s1.x) MAKEK(5, s1.y) MAKEK(6, s1.z) MAKEK(7, s1.w)
        MAKEK(8, s2.x) MAKEK(9, s2.y) MAKEK(10, s2.z) MAKEK(11, s2.w)
        MAKEK(12, s3.x) MAKEK(13, s3.y) MAKEK(14, s3.z) MAKEK(15, s3.w)
#undef MAKEK
        K[16] = (lane < 8)
                    ? ((((unsigned long long)mono(tot_own)) << 32) | (unsigned)~(unsigned)lane)
                    : 0ull;

        // local sorted top-3: two parallel insert chains + exact sorted merge
        unsigned long long a1 = 0ull, a2 = 0ull, a3 = 0ull;
        unsigned long long b1 = 0ull, b2 = 0ull, b3 = 0ull;
#define INSC(t1v, t2v, t3v, key)                                                \
        {                                                                       \
            unsigned long long k_ = (key);                                      \
            bool g1 = k_ > t1v, g2 = k_ > t2v, g3 = k_ > t3v;                   \
            unsigned long long x1 = g1 ? k_ : t1v;                              \
            unsigned long long x2 = g1 ? t1v : (g2 ? k_ : t2v);                 \
            t3v = (g1 | g2) ? t2v : (g3 ? k_ : t3v);                            \
            t1v = x1; t2v = x2;                                                 \
        }
        INSC(a1, a2, a3, K[0])  INSC(a1, a2, a3, K[2])  INSC(a1, a2, a3, K[4])
        INSC(a1, a2, a3, K[6])  INSC(a1, a2, a3, K[8])  INSC(a1, a2, a3, K[10])
        INSC(a1, a2, a3, K[12]) INSC(a1, a2, a3, K[14]) INSC(a1, a2, a3, K[16])
        INSC(b1, b2, b3, K[1])  INSC(b1, b2, b3, K[3])  INSC(b1, b2, b3, K[5])
        INSC(b1, b2, b3, K[7])  INSC(b1, b2, b3, K[9])  INSC(b1, b2, b3, K[11])
        INSC(b1, b2, b3, K[13]) INSC(b1, b2, b3, K[15])
#undef INSC
        unsigned long long m1, m2, m3;
        {
            unsigned long long u = (a1 < b1) ? a1 : b1;   // min of leaders
            m1 = (a1 < b1) ? b1 : a1;
            unsigned long long v = (a2 < b2) ? b2 : a2;   // max of seconds
            unsigned long long w = (a2 < b2) ? a2 : b2;   // min of seconds
            m2 = (u < v) ? v : u;
            unsigned long long mn = (u < v) ? u : v;
            unsigned long long X = (a2 > b1) ? a3 : ((b2 > a1) ? b3 : 0ull);
            unsigned long long wX = (w < X) ? X : w;
            m3 = (mn < wX) ? wX : mn;
        }

        // top-8 extraction: bound W strictly decreasing; ballot-shortcut tie-break
        unsigned long long W = ~0ull;
        unsigned selh_0, selh_1, selh_2, selh_3, selh_4, selh_5, selh_6, selh_7;
        unsigned sell_0, sell_1, sell_2, sell_3, sell_4, sell_5, sell_6, sell_7;
        bool dead = false;
#define ROUND(r)                                                                         \
        do {                                                                             \
            unsigned long long c = (m1 < W) ? m1 : ((m2 < W) ? m2 : ((m3 < W) ? m3 : 0ull)); \
            bool need = (c == 0ull) && !dead;                                            \
            if (__any(need)) {                                                           \
                if (need) {                                                              \
                    c = 0ull;                                                            \
                    _Pragma("unroll")                                                    \
                    for (int k = 0; k < 17; ++k) {                                       \
                        bool g = (K[k] < W) && (K[k] > c);                               \
                        c = g ? K[k] : c;                                                \
                    }                                                                    \
                    if (c == 0ull) dead = true;                                          \
                    else { m1 = c; m2 = ~0ull; m3 = ~0ull; }                             \
                }                                                                        \
            }                                                                            \
            unsigned ch = (unsigned)(c >> 32), cl = (unsigned)c;                         \
            unsigned M = wred_max_u32(ch);                                               \
            unsigned long long tb = __ballot(ch == M);                                   \
            unsigned L;                                                                  \
            if (__builtin_popcountll(tb) == 1) {                                         \
                L = rlaneu(cl, __builtin_ctzll(tb));                                     \
            } else {                                                                     \
                unsigned lo2 = (ch == M) ? cl : 0u;                                      \
                L = wred_max_u32(lo2);                                                   \
            }                                                                            \
            W = (((unsigned long long)M) << 32) | L;                                     \
            selh_##r = M; sell_##r = L;                                                  \
        } while (0);
        ROUND(0) ROUND(1) ROUND(2) ROUND(3) ROUND(4) ROUND(5) ROUND(6) ROUND(7)
#undef ROUND

        // uniform continuation-value tables (named scalars)
#define CBT(j) float cb8_##j = rlanef(contb_own, j); float cn8_##j = rlanef(contnb_own, j);
        REP8(CBT)
#undef CBT

        // per-lane decode: every lane decodes round `own` (lanes 8..63 = replicas)
        unsigned myM, myL;
        SEL8N(myM, (unsigned)own, selh);
        SEL8N(myL, (unsigned)own, sell);
        unsigned sel = ~myL;
        bool iscont = sel < 8u;
        unsigned e = sel - 8u;
        unsigned s = iscont ? sel : (e >> 7);
        unsigned lab = e & 127u;
        unsigned nd = sel8u(node8, s);
        unsigned pr = sel8u(par8, s);
        unsigned ln = sel8u(len8, s);
        unsigned la = sel8u(last8, s);
        float cbs, cns;
        SEL8N(cbs, s, cb8);
        SEL8N(cns, s, cn8);
        float npb_own = iscont ? cbs : LOG0f;
        float npnb_own = iscont ? cns : mono_inv(myM);  // ext pnb == sort value bitwise
        // A=(node<<12)|par (ext: node patched after hash, par = src node)
        unsigned A = iscont ? ((nd << 12) | pr) : nd;
        unsigned Bv = iscont ? ((ln << 7) | la) : (((ln + 1u) << 7) | lab);
        unsigned long long extbal = __ballot(!iscont);
        unsigned extmask = (unsigned)extbal & 0xFFu;  // bit r: round r was an extension

        // dedup-hash inserts: lane r handles new beam r (deterministic pre-ids)
        unsigned insRes = 0;
        if ((extmask >> lane) & 1u) {
            unsigned preid = 1u + 8u * (unsigned)t + (unsigned)lane;
            unsigned hkey = (nd << 7) | lab;
            unsigned entry = (hkey << 12) | preid;
            unsigned h = ((hkey * 2654435761u) >> 20) & HMASK;
            for (;;) {
                unsigned prev = atomicCAS(&hsh[h], HEMPTY, entry);
                if (prev == HEMPTY) { nodeinfo[preid] = hkey; insRes = preid; break; }
                if ((prev >> 12) == hkey) { insRes = prev & 0xFFFu; break; }
                h = (h + 1) & HMASK;
            }
        }
        // commit: gather per-round state from lane r; patch ext node ids
#pragma unroll
        for (int r = 0; r < 8; ++r) {
            unsigned Ar = rlaneu(A, r);
            unsigned Br = rlaneu(Bv, r);
            unsigned nd2 = Ar >> 12;
            if ((extmask >> r) & 1u) nd2 = rlaneu(insRes, r);  // uniform condition
            node8[r] = nd2; par8[r] = Ar & 0xFFFu;
            len8[r] = Br >> 7; last8[r] = Br & 127u;
        }
        node_own = sel8u(node8, (unsigned)own);
        par_own = sel8u(par8, (unsigned)own);
        len_own = (int)sel8u(len8, (unsigned)own);
        last_own = (int)sel8u(last8, (unsigned)own);
        pb_own = npb_own; pnb_own = npnb_own;

        s0 = n0; s1 = n1; s2 = n2; s3 = n3;
        prL = nprL; prH = nprH;
    }

    // final argmax of totals (ties -> lowest index), then parent-walk reconstruction
    unsigned fh, fl;
    {
        float tot = lae(pb_own, pnb_own);
        fh = (lane < 8) ? mono(tot) : 0u;
        fl = (lane < 8) ? ~(unsigned)lane : 0u;
    }
    {
        unsigned M = wred_max_u32(fh);
        unsigned lo2 = (fh == M) ? fl : 0u;
        fl = wred_max_u32(lo2);
    }
    const int best = (int)(~fl);
    int L = 0;
    unsigned c = 0;
#pragma unroll
    for (int j = 0; j < 8; ++j)
        if (best == j) { L = (int)len8[j]; c = node8[j]; }
    if (lane == 0) {
        for (int k = L - 1; k >= 0; --k) {
            unsigned info = nodeinfo[c];
            sh_seq[k] = (int)(info & 127u);
            c = info >> 7;
        }
    }
    __syncthreads();
    for (int j = lane; j < T; j += 64)
        out_seq[(size_t)b * T + j] = (j < L) ? sh_seq[j] : 0;
    if (lane == 0) out_len[b] = L;
}

extern "C" void kernel_launch(void* const* d_in, const int* in_sizes, int n_in,
                              void* d_out, int out_size, void* d_ws, size_t ws_size,
                              hipStream_t stream) {
    const float* probs = (const float*)d_in[0];
    const int* lengths = (const int*)d_in[1];
    // d_in[2] = beam_width (fixed 8, compiled in); d_in[3] = blank_index
    const int* blank_p = (const int*)d_in[3];
    const int B = in_sizes[1];
    const int T = in_sizes[0] / (B * VCAB);
    int* out = (int*)d_out;
    ctc_beam_kernel<<<B, 64, 0, stream>>>(probs, lengths, blank_p, out,
                                          out + (size_t)B * T, T);
}